// Round 1
// baseline (531.142 us; speedup 1.0000x reference)
//
#include <hip/hip_runtime.h>
#include <stdint.h>

#define D_MODEL 1024
#define BATCH 4
#define SEQ 4096
#define MROWS (BATCH*SEQ)     // 16384
#define CHUNK 64
#define NCHUNK (SEQ/CHUNK)    // 64

typedef unsigned short u16;
typedef __attribute__((ext_vector_type(8))) short short8;
typedef __attribute__((ext_vector_type(4))) float f32x4;
typedef __attribute__((ext_vector_type(4))) unsigned short u16x4;

__device__ __forceinline__ u16 f2bf(float f){
  uint32_t b = __builtin_bit_cast(uint32_t, f);
  b += 0x7FFFu + ((b >> 16) & 1u);
  return (u16)(b >> 16);
}
__device__ __forceinline__ float bf2f(u16 u){
  uint32_t b = ((uint32_t)u) << 16;
  return __builtin_bit_cast(float, b);
}

// ---------------- weight fp32 -> bf16 ----------------
__global__ void f2bf_vec(const float* __restrict__ in, u16* __restrict__ out, int n){
  int i = (blockIdx.x * 256 + threadIdx.x) * 4;
  if (i >= n) return;
  float4 v = *(const float4*)(in + i);
  u16x4 o; o.x = f2bf(v.x); o.y = f2bf(v.y); o.z = f2bf(v.z); o.w = f2bf(v.w);
  *(u16x4*)(out + i) = o;
}

// ---------------- layernorm -> bf16 ----------------
__global__ __launch_bounds__(256) void ln_kernel(const float* __restrict__ x,
    const float* __restrict__ g, const float* __restrict__ b, u16* __restrict__ h){
  int row = blockIdx.x;
  int tid = threadIdx.x, lane = tid & 63, wid = tid >> 6;
  const float* xr = x + (size_t)row * D_MODEL;
  float4 v = *(const float4*)(xr + tid * 4);
  float s  = v.x + v.y + v.z + v.w;
  float s2 = v.x*v.x + v.y*v.y + v.z*v.z + v.w*v.w;
#pragma unroll
  for (int off = 32; off > 0; off >>= 1){ s += __shfl_down(s, off); s2 += __shfl_down(s2, off); }
  __shared__ float red[8];
  if (lane == 0){ red[wid] = s; red[4 + wid] = s2; }
  __syncthreads();
  s  = red[0] + red[1] + red[2] + red[3];
  s2 = red[4] + red[5] + red[6] + red[7];
  float mu  = s * (1.f / D_MODEL);
  float var = s2 * (1.f / D_MODEL) - mu * mu;
  float rs  = rsqrtf(var + 1e-5f);
  int c = tid * 4;
  u16x4 o;
  o.x = f2bf((v.x - mu) * rs * g[c+0] + b[c+0]);
  o.y = f2bf((v.y - mu) * rs * g[c+1] + b[c+1]);
  o.z = f2bf((v.z - mu) * rs * g[c+2] + b[c+2]);
  o.w = f2bf((v.w - mu) * rs * g[c+3] + b[c+3]);
  *(u16x4*)(h + (size_t)row * D_MODEL + c) = o;
}

// ---------------- bf16 MFMA GEMM: C[M,N] = A[M,K] @ W[N,K]^T + bias ----------------
// 128x128 block tile, BK=32, 4 waves each computing 64x64 (4x4 frags of 16x16x32).
// EPI 0: store bf16(out).  EPI 1: store fp32(out + resid).
template<int EPI>
__global__ __launch_bounds__(256) void gemm_bf16_kernel(
    const u16* __restrict__ A, const u16* __restrict__ W,
    const float* __restrict__ bias,
    u16* __restrict__ outb, float* __restrict__ outf,
    const float* __restrict__ resid, int N, int K){
  __shared__ u16 As[128 * 32];
  __shared__ u16 Bs[128 * 32];
  int tid = threadIdx.x, wv = tid >> 6, lane = tid & 63;
  int m0 = blockIdx.y * 128, n0 = blockIdx.x * 128;
  int lrow = lane & 15, lko = (lane >> 4) * 8;
  int wm = (wv >> 1) * 64, wn = (wv & 1) * 64;
  f32x4 zero = {0.f, 0.f, 0.f, 0.f};
  f32x4 acc[4][4];
#pragma unroll
  for (int i = 0; i < 4; i++)
#pragma unroll
    for (int j = 0; j < 4; j++) acc[i][j] = zero;

  for (int kt = 0; kt < K; kt += 32){
#pragma unroll
    for (int j = 0; j < 2; j++){
      int e = j * 256 + tid;
      const u16* ga = A + (size_t)(m0 + (e >> 2)) * K + kt + (e & 3) * 8;
      const u16* gb = W + (size_t)(n0 + (e >> 2)) * K + kt + (e & 3) * 8;
      u16* la = As + (size_t)(j * 256 + wv * 64) * 8;  // wave-uniform base; HW adds lane*16B
      u16* lb = Bs + (size_t)(j * 256 + wv * 64) * 8;
      __builtin_amdgcn_global_load_lds((const __attribute__((address_space(1))) void*)ga,
                                       (__attribute__((address_space(3))) void*)la, 16, 0, 0);
      __builtin_amdgcn_global_load_lds((const __attribute__((address_space(1))) void*)gb,
                                       (__attribute__((address_space(3))) void*)lb, 16, 0, 0);
    }
    __syncthreads();
    short8 af[4], bfr[4];
#pragma unroll
    for (int f = 0; f < 4; f++){
      af[f]  = *(const short8*)(As + (wm + f * 16 + lrow) * 32 + lko);
      bfr[f] = *(const short8*)(Bs + (wn + f * 16 + lrow) * 32 + lko);
    }
#pragma unroll
    for (int fm = 0; fm < 4; fm++)
#pragma unroll
      for (int fn = 0; fn < 4; fn++)
        acc[fm][fn] = __builtin_amdgcn_mfma_f32_16x16x32_bf16(af[fm], bfr[fn], acc[fm][fn], 0, 0, 0);
    __syncthreads();
  }
  // epilogue: D row = (lane>>4)*4 + i, col = lane&15 (m89-verified layout)
#pragma unroll
  for (int fm = 0; fm < 4; fm++){
    int r0 = m0 + wm + fm * 16 + (lane >> 4) * 4;
#pragma unroll
    for (int fn = 0; fn < 4; fn++){
      int c = n0 + wn + fn * 16 + lrow;
      float bv = bias[c];
#pragma unroll
      for (int i = 0; i < 4; i++){
        float val = acc[fm][fn][i] + bv;
        size_t o = (size_t)(r0 + i) * N + c;
        if (EPI == 0) outb[o] = f2bf(val);
        else          outf[o] = val + resid[o];
      }
    }
  }
}

// ---------------- depthwise causal conv1d (K=4) ----------------
__global__ void conv_kernel(const u16* __restrict__ uv, const float* __restrict__ wc,
                            const float* __restrict__ bc, u16* __restrict__ uc){
  int idx = blockIdx.x * 256 + threadIdx.x;
  int d = idx & (D_MODEL - 1);
  int m = idx >> 10;
  int l = m & (SEQ - 1);
  float acc = bc[d];
#pragma unroll
  for (int k = 0; k < 4; k++){
    int ll = l - 3 + k;
    if (ll >= 0)
      acc += bf2f(uv[(size_t)(m - 3 + k) * 2048 + d]) * wc[d * 4 + k];
  }
  uc[idx] = f2bf(acc);
}

// ---------------- selective scan, pass A: per-chunk P (decay prod) and S (local end state) ----------------
__global__ void scanA(const u16* __restrict__ dbc, const u16* __restrict__ uc,
                      float* __restrict__ P, float* __restrict__ S){
  int idx = blockIdx.x * 256 + threadIdx.x;   // over BATCH*NCHUNK*1024
  int n = idx & 1023;
  int c = (idx >> 10) & (NCHUNK - 1);
  int b = idx >> 16;
  size_t mbase = (size_t)b * SEQ + c * CHUNK;
  float Pv = 1.f, Sv = 0.f;
  for (int t = 0; t < CHUNK; t++){
    size_t m = mbase + t;
    float dr = bf2f(dbc[m * 3072 + n]);
    float bm = bf2f(dbc[m * 3072 + 1024 + n]);
    float u  = bf2f(uc[m * 1024 + n]);
    float dec = 1.f / (1.f + __expf(dr));   // exp(-softplus(dr)) == sigmoid(-dr), exact identity
    Pv *= dec;
    Sv = Sv * dec + u * bm;
  }
  P[idx] = Pv; S[idx] = Sv;
}

// ---------------- pass B: chunk-level scan for entering states ----------------
__global__ void scanB(const float* __restrict__ P, const float* __restrict__ S,
                      float* __restrict__ Hin){
  int idx = blockIdx.x * 256 + threadIdx.x;  // over BATCH*1024
  int n = idx & 1023, b = idx >> 10;
  float H = 0.f;
  for (int c = 0; c < NCHUNK; c++){
    int o = (b * NCHUNK + c) * 1024 + n;
    Hin[o] = H;
    H = H * P[o] + S[o];
  }
}

// ---------------- pass C: recompute local states with entering state, reduce y[b,t] ----------------
__global__ __launch_bounds__(1024) void scanC(const u16* __restrict__ dbc, const u16* __restrict__ uc,
                                              const float* __restrict__ Hin, float* __restrict__ y){
  int b = blockIdx.x >> 6, c = blockIdx.x & (NCHUNK - 1);
  int n = threadIdx.x, wid = n >> 6, lane = n & 63;
  __shared__ float part[CHUNK][16];
  float h = Hin[(b * NCHUNK + c) * 1024 + n];
  size_t mbase = (size_t)b * SEQ + c * CHUNK;
  for (int t = 0; t < CHUNK; t++){
    size_t m = mbase + t;
    float dr = bf2f(dbc[m * 3072 + n]);
    float bm = bf2f(dbc[m * 3072 + 1024 + n]);
    float cm = bf2f(dbc[m * 3072 + 2048 + n]);
    float u  = bf2f(uc[m * 1024 + n]);
    float dec = 1.f / (1.f + __expf(dr));
    h = h * dec + u * bm;
    float contrib = h * cm;
#pragma unroll
    for (int off = 32; off > 0; off >>= 1) contrib += __shfl_down(contrib, off);
    if (lane == 0) part[t][wid] = contrib;
  }
  __syncthreads();
  if (n < CHUNK){
    float s = 0.f;
#pragma unroll
    for (int w2 = 0; w2 < 16; w2++) s += part[n][w2];
    y[mbase + n] = s;
  }
}

// ---------------- gate: gg = bf16( y[m] * sigmoid(v) ) ----------------
__global__ void gate_kernel(const u16* __restrict__ uv, const float* __restrict__ y,
                            u16* __restrict__ gg){
  int idx = blockIdx.x * 256 + threadIdx.x;
  int d = idx & (D_MODEL - 1);
  int m = idx >> 10;
  float v = bf2f(uv[(size_t)m * 2048 + D_MODEL + d]);
  float s = 1.f / (1.f + __expf(-v));
  gg[idx] = f2bf(y[m] * s);
}

extern "C" void kernel_launch(void* const* d_in, const int* in_sizes, int n_in,
                              void* d_out, int out_size, void* d_ws, size_t ws_size,
                              hipStream_t stream) {
  const float* x      = (const float*)d_in[0];
  const float* ln_g   = (const float*)d_in[1];
  const float* ln_b   = (const float*)d_in[2];
  const float* w_in   = (const float*)d_in[3];
  const float* b_in   = (const float*)d_in[4];
  const float* w_conv = (const float*)d_in[5];
  const float* b_conv = (const float*)d_in[6];
  const float* w_delta= (const float*)d_in[7];
  const float* b_delta= (const float*)d_in[8];
  const float* w_B    = (const float*)d_in[9];
  const float* b_B    = (const float*)d_in[10];
  const float* w_C    = (const float*)d_in[11];
  const float* b_C    = (const float*)d_in[12];
  const float* w_out  = (const float*)d_in[13];
  const float* b_out  = (const float*)d_in[14];

  char* w = (char*)d_ws;
  u16* w_in_bf  = (u16*)w; w += (size_t)2 * 1024 * 1024 * 2;   // 4 MB
  u16* wcat_bf  = (u16*)w; w += (size_t)3 * 1024 * 1024 * 2;   // 6 MB (delta|B|C rows)
  u16* w_out_bf = (u16*)w; w += (size_t)1024 * 1024 * 2;       // 2 MB
  float* bcat   = (float*)w; w += 16384;                        // 3072 floats, padded
  u16* h_bf     = (u16*)w; w += (size_t)MROWS * 1024 * 2;      // 32 MB
  u16* uv_bf    = (u16*)w; w += (size_t)MROWS * 2048 * 2;      // 64 MB
  u16* uc_bf    = (u16*)w; w += (size_t)MROWS * 1024 * 2;      // 32 MB
  u16* dbc_bf   = (u16*)w; w += (size_t)MROWS * 3072 * 2;      // 96 MB
  float* P      = (float*)w; w += (size_t)BATCH * NCHUNK * 1024 * 4;
  float* S      = (float*)w; w += (size_t)BATCH * NCHUNK * 1024 * 4;
  float* Hin    = (float*)w; w += (size_t)BATCH * NCHUNK * 1024 * 4;
  float* yv     = (float*)w; w += (size_t)MROWS * 4;
  u16* gg       = h_bf;   // reuse: h dead after GEMM1

  // weights -> bf16
  f2bf_vec<<<2048, 256, 0, stream>>>(w_in,    w_in_bf,              2 * 1024 * 1024);
  f2bf_vec<<<1024, 256, 0, stream>>>(w_delta, wcat_bf,              1024 * 1024);
  f2bf_vec<<<1024, 256, 0, stream>>>(w_B,     wcat_bf + 1024*1024,  1024 * 1024);
  f2bf_vec<<<1024, 256, 0, stream>>>(w_C,     wcat_bf + 2*1024*1024,1024 * 1024);
  f2bf_vec<<<1024, 256, 0, stream>>>(w_out,   w_out_bf,             1024 * 1024);
  hipMemcpyAsync(bcat,        b_delta, 1024 * sizeof(float), hipMemcpyDeviceToDevice, stream);
  hipMemcpyAsync(bcat + 1024, b_B,     1024 * sizeof(float), hipMemcpyDeviceToDevice, stream);
  hipMemcpyAsync(bcat + 2048, b_C,     1024 * sizeof(float), hipMemcpyDeviceToDevice, stream);

  ln_kernel<<<MROWS, 256, 0, stream>>>(x, ln_g, ln_b, h_bf);

  // in_proj: uv[16384,2048]
  gemm_bf16_kernel<0><<<dim3(2048/128, MROWS/128), 256, 0, stream>>>(
      h_bf, w_in_bf, b_in, uv_bf, nullptr, nullptr, 2048, 1024);

  conv_kernel<<<(MROWS * 1024) / 256, 256, 0, stream>>>(uv_bf, w_conv, b_conv, uc_bf);

  // delta|B|C fused: dbc[16384,3072]
  gemm_bf16_kernel<0><<<dim3(3072/128, MROWS/128), 256, 0, stream>>>(
      uc_bf, wcat_bf, bcat, dbc_bf, nullptr, nullptr, 3072, 1024);

  scanA<<<(BATCH * NCHUNK * 1024) / 256, 256, 0, stream>>>(dbc_bf, uc_bf, P, S);
  scanB<<<(BATCH * 1024) / 256, 256, 0, stream>>>(P, S, Hin);
  scanC<<<BATCH * NCHUNK, 1024, 0, stream>>>(dbc_bf, uc_bf, Hin, yv);

  gate_kernel<<<(MROWS * 1024) / 256, 256, 0, stream>>>(uv_bf, yv, gg);

  // out_proj + bias + residual -> d_out (fp32)
  gemm_bf16_kernel<1><<<dim3(1024/128, MROWS/128), 256, 0, stream>>>(
      gg, w_out_bf, b_out, nullptr, (float*)d_out, x, 1024, 1024);
}

// Round 2
// 445.872 us; speedup vs baseline: 1.1912x; 1.1912x over previous
//
#include <hip/hip_runtime.h>
#include <stdint.h>

#define D_MODEL 1024
#define BATCH 4
#define SEQ 4096
#define MROWS (BATCH*SEQ)     // 16384
#define CHUNK 64
#define NCHUNK (SEQ/CHUNK)    // 64

typedef unsigned short u16;
typedef __attribute__((ext_vector_type(8))) short short8;
typedef __attribute__((ext_vector_type(4))) float f32x4;
typedef __attribute__((ext_vector_type(4))) unsigned short u16x4;

__device__ __forceinline__ u16 f2bf(float f){
  uint32_t b = __builtin_bit_cast(uint32_t, f);
  b += 0x7FFFu + ((b >> 16) & 1u);
  return (u16)(b >> 16);
}
__device__ __forceinline__ float bf2f(u16 u){
  uint32_t b = ((uint32_t)u) << 16;
  return __builtin_bit_cast(float, b);
}

// ---------------- weight fp32 -> bf16 ----------------
__global__ void f2bf_vec(const float* __restrict__ in, u16* __restrict__ out, int n){
  int i = (blockIdx.x * 256 + threadIdx.x) * 4;
  if (i >= n) return;
  float4 v = *(const float4*)(in + i);
  u16x4 o; o.x = f2bf(v.x); o.y = f2bf(v.y); o.z = f2bf(v.z); o.w = f2bf(v.w);
  *(u16x4*)(out + i) = o;
}

// ---------------- layernorm -> bf16 ----------------
__global__ __launch_bounds__(256) void ln_kernel(const float* __restrict__ x,
    const float* __restrict__ g, const float* __restrict__ b, u16* __restrict__ h){
  int row = blockIdx.x;
  int tid = threadIdx.x, lane = tid & 63, wid = tid >> 6;
  const float* xr = x + (size_t)row * D_MODEL;
  float4 v = *(const float4*)(xr + tid * 4);
  float s  = v.x + v.y + v.z + v.w;
  float s2 = v.x*v.x + v.y*v.y + v.z*v.z + v.w*v.w;
#pragma unroll
  for (int off = 32; off > 0; off >>= 1){ s += __shfl_down(s, off); s2 += __shfl_down(s2, off); }
  __shared__ float red[8];
  if (lane == 0){ red[wid] = s; red[4 + wid] = s2; }
  __syncthreads();
  s  = red[0] + red[1] + red[2] + red[3];
  s2 = red[4] + red[5] + red[6] + red[7];
  float mu  = s * (1.f / D_MODEL);
  float var = s2 * (1.f / D_MODEL) - mu * mu;
  float rs  = rsqrtf(var + 1e-5f);
  int c = tid * 4;
  u16x4 o;
  o.x = f2bf((v.x - mu) * rs * g[c+0] + b[c+0]);
  o.y = f2bf((v.y - mu) * rs * g[c+1] + b[c+1]);
  o.z = f2bf((v.z - mu) * rs * g[c+2] + b[c+2]);
  o.w = f2bf((v.w - mu) * rs * g[c+3] + b[c+3]);
  *(u16x4*)(h + (size_t)row * D_MODEL + c) = o;
}

// ---------------- 256x256 8-phase bf16 MFMA GEMM ----------------
// C[M,N] = A[M,K] @ W[N,K]^T + bias.  8 waves (2M x 4N), BK=64, 2 K-tiles/iter,
// 8 phases/iter, LDS 128KB double-buffered, XOR-swizzled (byte ^= (row&7)<<4),
// counted vmcnt(4) at phases 4/8 only, setprio(1) around MFMA clusters.
// EPI 0: store bf16(out).  EPI 1: store fp32(out + resid).
template<int EPI>
__global__ __launch_bounds__(512, 2) void gemm256(
    const u16* __restrict__ A, const u16* __restrict__ W,
    const float* __restrict__ bias,
    u16* __restrict__ outb, float* __restrict__ outf,
    const float* __restrict__ resid, int N, int K){
  __shared__ char lds[131072];   // A: [0,64KB) 2 bufs; B: [64KB,128KB) 2 bufs
  const int tid = threadIdx.x, wid = tid >> 6, lane = tid & 63;
  const int wm = wid >> 2, wn = wid & 3;
  const int lrow = lane & 15, khi = lane >> 4;

  // XCD-aware swizzle (grid is a multiple of 8 for all our shapes)
  int nwg = gridDim.x;
  int cpx = nwg >> 3;
  int bid = blockIdx.x;
  int wg = (bid & 7) * cpx + (bid >> 3);
  int ntile = N >> 8;
  int by = wg / ntile, bx = wg % ntile;
  int m0 = by << 8, n0 = bx << 8;

  f32x4 acc[8][4];
  f32x4 zero = {0.f, 0.f, 0.f, 0.f};
#pragma unroll
  for (int i = 0; i < 8; i++)
#pragma unroll
    for (int j = 0; j < 4; j++) acc[i][j] = zero;
  short8 bfrag[4][2];

  // stage one 128-row x 64-col half-tile: linear LDS dest, inverse-swizzled global src
  auto stageA = [&](int h, int kt, int p){
#pragma unroll
    for (int j = 0; j < 2; j++){
      int e = tid + j * 512;
      int r = h * 128 + (e >> 3);
      int cb2 = ((e & 7) * 16) ^ ((r & 7) << 4);
      const u16* gp = A + (size_t)(m0 + r) * K + kt + (cb2 >> 1);
      unsigned lb = (unsigned)(p * 32768 + h * 16384 + (j * 512 + wid * 64) * 16);
      __builtin_amdgcn_global_load_lds((const __attribute__((address_space(1))) void*)gp,
                                       (__attribute__((address_space(3))) void*)(lds + lb), 16, 0, 0);
    }
  };
  auto stageB = [&](int h, int kt, int p){
#pragma unroll
    for (int j = 0; j < 2; j++){
      int e = tid + j * 512;
      int r = h * 128 + (e >> 3);
      int cb2 = ((e & 7) * 16) ^ ((r & 7) << 4);
      const u16* gp = W + (size_t)(n0 + r) * K + kt + (cb2 >> 1);
      unsigned lb = (unsigned)(65536 + p * 32768 + h * 16384 + (j * 512 + wid * 64) * 16);
      __builtin_amdgcn_global_load_lds((const __attribute__((address_space(1))) void*)gp,
                                       (__attribute__((address_space(3))) void*)(lds + lb), 16, 0, 0);
    }
  };
  // swizzled ds_read of one 16B fragment slice
  auto rdfrag = [&](int base, int r, int cb) -> short8 {
    int addr = base + r * 128 + (cb ^ ((r & 7) << 4));
    return *(const short8*)(lds + addr);
  };

  const int nIter = K >> 7;   // 2 K-tiles (BK=64) per iteration

  // prologue: B(k0), A(k0) -> buf0 ; B(k1) -> buf1 ; wait all of k0 landed
  stageB(0, 0, 0); stageB(1, 0, 0);
  stageA(0, 0, 0); stageA(1, 0, 0);
  stageB(0, 64, 1); stageB(1, 64, 1);
  asm volatile("s_waitcnt vmcnt(4)" ::: "memory");
  __builtin_amdgcn_s_barrier();

  for (int i = 0; i < nIter; ++i){
    const bool pre = (i < nIter - 1);
    const int ktA1 = (2 * i + 1) << 6;   // K-tile k1 (consumed this iter, phases 4-7)
    const int ktN  = (2 * i + 2) << 6;   // K-tile k2 (next iter, buf0)
    const int ktN1 = (2 * i + 3) << 6;   // K-tile k3 (next iter, buf1)
#pragma unroll
    for (int half = 0; half < 2; ++half){        // K-tile 2i+half from buffer `half`
      const int abase = half * 32768;
      const int bbase = 65536 + half * 32768;
#pragma unroll
      for (int q = 0; q < 4; ++q){               // phase within K-tile
        // --- ds reads for this phase's MFMAs ---
        if (q == 0){
#pragma unroll
          for (int nf = 0; nf < 4; nf++)
#pragma unroll
            for (int ks = 0; ks < 2; ks++)
              bfrag[nf][ks] = rdfrag(bbase, wn * 64 + nf * 16 + lrow, ks * 64 + khi * 16);
        }
        short8 a[2][2];
#pragma unroll
        for (int mi = 0; mi < 2; mi++)
#pragma unroll
          for (int ks = 0; ks < 2; ks++)
            a[mi][ks] = rdfrag(abase, wm * 128 + (q * 2 + mi) * 16 + lrow, ks * 64 + khi * 16);
        // --- stage one half-tile (region freed >=1 barrier-pair ago) ---
        const int g = half * 4 + q;
        if      (g == 0){ stageA(0, ktA1, 1); }
        else if (g == 1){ stageA(1, ktA1, 1); }
        else if (g == 2){ if (pre) stageB(0, ktN, 0); }
        else if (g == 3){ if (pre) stageB(1, ktN, 0); }
        else if (g == 4){ if (pre) stageA(0, ktN, 0); }
        else if (g == 5){ if (pre) stageA(1, ktN, 0); }
        else if (g == 6){ if (pre) stageB(0, ktN1, 1); }
        else            { if (pre) stageB(1, ktN1, 1); }
        __builtin_amdgcn_s_barrier();
        __builtin_amdgcn_s_setprio(1);
#pragma unroll
        for (int ks = 0; ks < 2; ks++)
#pragma unroll
          for (int mi = 0; mi < 2; mi++)
#pragma unroll
            for (int nf = 0; nf < 4; nf++)
              acc[q * 2 + mi][nf] = __builtin_amdgcn_mfma_f32_16x16x32_bf16(
                  a[mi][ks], bfrag[nf][ks], acc[q * 2 + mi][nf], 0, 0, 0);
        __builtin_amdgcn_s_setprio(0);
        if (q == 3){
          if (pre) asm volatile("s_waitcnt vmcnt(4)" ::: "memory");
          else     asm volatile("s_waitcnt vmcnt(0)" ::: "memory");
        }
        __builtin_amdgcn_s_barrier();
      }
    }
  }

  // epilogue: D row = (lane>>4)*4 + i, col = lane&15 (m89-verified layout)
#pragma unroll
  for (int mf = 0; mf < 8; mf++){
    int r0 = m0 + wm * 128 + mf * 16 + khi * 4;
#pragma unroll
    for (int nf = 0; nf < 4; nf++){
      int c = n0 + wn * 64 + nf * 16 + lrow;
      float bv = bias[c];
#pragma unroll
      for (int i2 = 0; i2 < 4; i2++){
        float val = acc[mf][nf][i2] + bv;
        size_t o = (size_t)(r0 + i2) * N + c;
        if (EPI == 0) outb[o] = f2bf(val);
        else          outf[o] = val + resid[o];
      }
    }
  }
}

// ---------------- depthwise causal conv1d (K=4) ----------------
__global__ void conv_kernel(const u16* __restrict__ uv, const float* __restrict__ wc,
                            const float* __restrict__ bc, u16* __restrict__ uc){
  int idx = blockIdx.x * 256 + threadIdx.x;
  int d = idx & (D_MODEL - 1);
  int m = idx >> 10;
  int l = m & (SEQ - 1);
  float acc = bc[d];
#pragma unroll
  for (int k = 0; k < 4; k++){
    int ll = l - 3 + k;
    if (ll >= 0)
      acc += bf2f(uv[(size_t)(m - 3 + k) * 2048 + d]) * wc[d * 4 + k];
  }
  uc[idx] = f2bf(acc);
}

// ---------------- selective scan, pass A ----------------
__global__ void scanA(const u16* __restrict__ dbc, const u16* __restrict__ uc,
                      float* __restrict__ P, float* __restrict__ S){
  int idx = blockIdx.x * 256 + threadIdx.x;   // over BATCH*NCHUNK*1024
  int n = idx & 1023;
  int c = (idx >> 10) & (NCHUNK - 1);
  int b = idx >> 16;
  size_t mbase = (size_t)b * SEQ + c * CHUNK;
  float Pv = 1.f, Sv = 0.f;
  for (int t = 0; t < CHUNK; t++){
    size_t m = mbase + t;
    float dr = bf2f(dbc[m * 3072 + n]);
    float bm = bf2f(dbc[m * 3072 + 1024 + n]);
    float u  = bf2f(uc[m * 1024 + n]);
    float dec = 1.f / (1.f + __expf(dr));   // exp(-softplus(dr)) == sigmoid(-dr)
    Pv *= dec;
    Sv = Sv * dec + u * bm;
  }
  P[idx] = Pv; S[idx] = Sv;
}

// ---------------- pass B: chunk-level scan ----------------
__global__ void scanB(const float* __restrict__ P, const float* __restrict__ S,
                      float* __restrict__ Hin){
  int idx = blockIdx.x * 256 + threadIdx.x;  // over BATCH*1024
  int n = idx & 1023, b = idx >> 10;
  float H = 0.f;
  for (int c = 0; c < NCHUNK; c++){
    int o = (b * NCHUNK + c) * 1024 + n;
    Hin[o] = H;
    H = H * P[o] + S[o];
  }
}

// ---------------- pass C: recompute + reduce y[b,t] ----------------
__global__ __launch_bounds__(1024) void scanC(const u16* __restrict__ dbc, const u16* __restrict__ uc,
                                              const float* __restrict__ Hin, float* __restrict__ y){
  int b = blockIdx.x >> 6, c = blockIdx.x & (NCHUNK - 1);
  int n = threadIdx.x, wid = n >> 6, lane = n & 63;
  __shared__ float part[CHUNK][16];
  float h = Hin[(b * NCHUNK + c) * 1024 + n];
  size_t mbase = (size_t)b * SEQ + c * CHUNK;
  for (int t = 0; t < CHUNK; t++){
    size_t m = mbase + t;
    float dr = bf2f(dbc[m * 3072 + n]);
    float bm = bf2f(dbc[m * 3072 + 1024 + n]);
    float cm = bf2f(dbc[m * 3072 + 2048 + n]);
    float u  = bf2f(uc[m * 1024 + n]);
    float dec = 1.f / (1.f + __expf(dr));
    h = h * dec + u * bm;
    float contrib = h * cm;
#pragma unroll
    for (int off = 32; off > 0; off >>= 1) contrib += __shfl_down(contrib, off);
    if (lane == 0) part[t][wid] = contrib;
  }
  __syncthreads();
  if (n < CHUNK){
    float s = 0.f;
#pragma unroll
    for (int w2 = 0; w2 < 16; w2++) s += part[n][w2];
    y[mbase + n] = s;
  }
}

// ---------------- gate ----------------
__global__ void gate_kernel(const u16* __restrict__ uv, const float* __restrict__ y,
                            u16* __restrict__ gg){
  int idx = blockIdx.x * 256 + threadIdx.x;
  int d = idx & (D_MODEL - 1);
  int m = idx >> 10;
  float v = bf2f(uv[(size_t)m * 2048 + D_MODEL + d]);
  float s = 1.f / (1.f + __expf(-v));
  gg[idx] = f2bf(y[m] * s);
}

extern "C" void kernel_launch(void* const* d_in, const int* in_sizes, int n_in,
                              void* d_out, int out_size, void* d_ws, size_t ws_size,
                              hipStream_t stream) {
  const float* x      = (const float*)d_in[0];
  const float* ln_g   = (const float*)d_in[1];
  const float* ln_b   = (const float*)d_in[2];
  const float* w_in   = (const float*)d_in[3];
  const float* b_in   = (const float*)d_in[4];
  const float* w_conv = (const float*)d_in[5];
  const float* b_conv = (const float*)d_in[6];
  const float* w_delta= (const float*)d_in[7];
  const float* b_delta= (const float*)d_in[8];
  const float* w_B    = (const float*)d_in[9];
  const float* b_B    = (const float*)d_in[10];
  const float* w_C    = (const float*)d_in[11];
  const float* b_C    = (const float*)d_in[12];
  const float* w_out  = (const float*)d_in[13];
  const float* b_out  = (const float*)d_in[14];

  char* w = (char*)d_ws;
  u16* w_in_bf  = (u16*)w; w += (size_t)2 * 1024 * 1024 * 2;   // 4 MB
  u16* wcat_bf  = (u16*)w; w += (size_t)3 * 1024 * 1024 * 2;   // 6 MB (delta|B|C rows)
  u16* w_out_bf = (u16*)w; w += (size_t)1024 * 1024 * 2;       // 2 MB
  float* bcat   = (float*)w; w += 16384;                        // 3072 floats, padded
  u16* h_bf     = (u16*)w; w += (size_t)MROWS * 1024 * 2;      // 32 MB
  u16* uv_bf    = (u16*)w; w += (size_t)MROWS * 2048 * 2;      // 64 MB
  u16* uc_bf    = (u16*)w; w += (size_t)MROWS * 1024 * 2;      // 32 MB
  u16* dbc_bf   = (u16*)w; w += (size_t)MROWS * 3072 * 2;      // 96 MB
  float* P      = (float*)w; w += (size_t)BATCH * NCHUNK * 1024 * 4;
  float* S      = (float*)w; w += (size_t)BATCH * NCHUNK * 1024 * 4;
  float* Hin    = (float*)w; w += (size_t)BATCH * NCHUNK * 1024 * 4;
  float* yv     = (float*)w; w += (size_t)MROWS * 4;
  u16* gg       = h_bf;   // reuse: h dead after GEMM1

  // weights -> bf16
  f2bf_vec<<<2048, 256, 0, stream>>>(w_in,    w_in_bf,              2 * 1024 * 1024);
  f2bf_vec<<<1024, 256, 0, stream>>>(w_delta, wcat_bf,              1024 * 1024);
  f2bf_vec<<<1024, 256, 0, stream>>>(w_B,     wcat_bf + 1024*1024,  1024 * 1024);
  f2bf_vec<<<1024, 256, 0, stream>>>(w_C,     wcat_bf + 2*1024*1024,1024 * 1024);
  f2bf_vec<<<1024, 256, 0, stream>>>(w_out,   w_out_bf,             1024 * 1024);
  hipMemcpyAsync(bcat,        b_delta, 1024 * sizeof(float), hipMemcpyDeviceToDevice, stream);
  hipMemcpyAsync(bcat + 1024, b_B,     1024 * sizeof(float), hipMemcpyDeviceToDevice, stream);
  hipMemcpyAsync(bcat + 2048, b_C,     1024 * sizeof(float), hipMemcpyDeviceToDevice, stream);

  ln_kernel<<<MROWS, 256, 0, stream>>>(x, ln_g, ln_b, h_bf);

  // in_proj: uv[16384,2048]
  gemm256<0><<<dim3((2048/256) * (MROWS/256)), 512, 0, stream>>>(
      h_bf, w_in_bf, b_in, uv_bf, nullptr, nullptr, 2048, 1024);

  conv_kernel<<<(MROWS * 1024) / 256, 256, 0, stream>>>(uv_bf, w_conv, b_conv, uc_bf);

  // delta|B|C fused: dbc[16384,3072]
  gemm256<0><<<dim3((3072/256) * (MROWS/256)), 512, 0, stream>>>(
      uc_bf, wcat_bf, bcat, dbc_bf, nullptr, nullptr, 3072, 1024);

  scanA<<<(BATCH * NCHUNK * 1024) / 256, 256, 0, stream>>>(dbc_bf, uc_bf, P, S);
  scanB<<<(BATCH * 1024) / 256, 256, 0, stream>>>(P, S, Hin);
  scanC<<<BATCH * NCHUNK, 1024, 0, stream>>>(dbc_bf, uc_bf, Hin, yv);

  gate_kernel<<<(MROWS * 1024) / 256, 256, 0, stream>>>(uv_bf, yv, gg);

  // out_proj + bias + residual -> d_out (fp32)
  gemm256<1><<<dim3((1024/256) * (MROWS/256)), 512, 0, stream>>>(
      gg, w_out_bf, b_out, nullptr, (float*)d_out, x, 1024, 1024);
}

// Round 3
// 401.823 us; speedup vs baseline: 1.3218x; 1.1096x over previous
//
#include <hip/hip_runtime.h>
#include <stdint.h>

#define D_MODEL 1024
#define KDIM 1024             // all three GEMMs have K=1024 (compile-time)
#define BATCH 4
#define SEQ 4096
#define MROWS (BATCH*SEQ)     // 16384
#define CHUNK 64
#define NCHUNK (SEQ/CHUNK)    // 64

typedef unsigned short u16;
typedef __attribute__((ext_vector_type(8))) short short8;
typedef __attribute__((ext_vector_type(4))) float f32x4;
typedef __attribute__((ext_vector_type(4))) unsigned short u16x4;

__device__ __forceinline__ u16 f2bf(float f){
  uint32_t b = __builtin_bit_cast(uint32_t, f);
  b += 0x7FFFu + ((b >> 16) & 1u);
  return (u16)(b >> 16);
}
__device__ __forceinline__ float bf2f(u16 u){
  uint32_t b = ((uint32_t)u) << 16;
  return __builtin_bit_cast(float, b);
}

// ---------------- weight fp32 -> bf16 ----------------
__global__ void f2bf_vec(const float* __restrict__ in, u16* __restrict__ out, int n){
  int i = (blockIdx.x * 256 + threadIdx.x) * 4;
  if (i >= n) return;
  float4 v = *(const float4*)(in + i);
  u16x4 o; o.x = f2bf(v.x); o.y = f2bf(v.y); o.z = f2bf(v.z); o.w = f2bf(v.w);
  *(u16x4*)(out + i) = o;
}

// ---------------- layernorm -> bf16 ----------------
__global__ __launch_bounds__(256) void ln_kernel(const float* __restrict__ x,
    const float* __restrict__ g, const float* __restrict__ b, u16* __restrict__ h){
  int row = blockIdx.x;
  int tid = threadIdx.x, lane = tid & 63, wid = tid >> 6;
  const float* xr = x + (size_t)row * D_MODEL;
  float4 v = *(const float4*)(xr + tid * 4);
  float s  = v.x + v.y + v.z + v.w;
  float s2 = v.x*v.x + v.y*v.y + v.z*v.z + v.w*v.w;
#pragma unroll
  for (int off = 32; off > 0; off >>= 1){ s += __shfl_down(s, off); s2 += __shfl_down(s2, off); }
  __shared__ float red[8];
  if (lane == 0){ red[wid] = s; red[4 + wid] = s2; }
  __syncthreads();
  s  = red[0] + red[1] + red[2] + red[3];
  s2 = red[4] + red[5] + red[6] + red[7];
  float mu  = s * (1.f / D_MODEL);
  float var = s2 * (1.f / D_MODEL) - mu * mu;
  float rs  = rsqrtf(var + 1e-5f);
  int c = tid * 4;
  u16x4 o;
  o.x = f2bf((v.x - mu) * rs * g[c+0] + b[c+0]);
  o.y = f2bf((v.y - mu) * rs * g[c+1] + b[c+1]);
  o.z = f2bf((v.z - mu) * rs * g[c+2] + b[c+2]);
  o.w = f2bf((v.w - mu) * rs * g[c+3] + b[c+3]);
  *(u16x4*)(h + (size_t)row * D_MODEL + c) = o;
}

// ---------------- 256x256 8-phase bf16 MFMA GEMM (K=1024 compile-time) ----------------
// C[M,N] = A[M,K] @ W[N,K]^T + bias.  8 waves (2M x 4N), BK=64, 2 K-tiles/iter,
// 8 phases/iter, LDS 128KB double-buffered, XOR-swizzle byte^=(row&7)<<4 with
// all swizzle math hoisted to 4 per-thread constants (r&7 == lrow&7 for every
// fragment). Counted vmcnt(4) at phases 4/8 only, setprio(1) around MFMA.
// EPI 0: store bf16(out).  EPI 1: store fp32(out + resid).
template<int EPI>
__global__ __launch_bounds__(512, 2) void gemm256(
    const u16* __restrict__ A, const u16* __restrict__ W,
    const float* __restrict__ bias,
    u16* __restrict__ outb, float* __restrict__ outf,
    const float* __restrict__ resid, int N){
  __shared__ char lds[131072];   // A: [0,64KB) 2 bufs; B: [64KB,128KB) 2 bufs
  const int tid = threadIdx.x, wid = tid >> 6, lane = tid & 63;
  const int wm = wid >> 2, wn = wid & 3;
  const int lrow = lane & 15, khi = lane >> 4;

  // XCD-aware swizzle (grid is a multiple of 8 for all our shapes)
  int nwg = gridDim.x;
  int cpx = nwg >> 3;
  int bid = blockIdx.x;
  int wg = (bid & 7) * cpx + (bid >> 3);
  int ntile = N >> 8;
  int by = wg / ntile, bx = wg % ntile;
  int m0 = by << 8, n0 = bx << 8;

  f32x4 acc[8][4];
  f32x4 zero = {0.f, 0.f, 0.f, 0.f};
#pragma unroll
  for (int i = 0; i < 8; i++)
#pragma unroll
    for (int j = 0; j < 4; j++) acc[i][j] = zero;
  short8 bfrag[4][2];

  // --- hoisted per-thread swizzled LDS read offsets (bytes, within a buffer) ---
  const int xorq = (lrow & 7) << 4;
  const int aK0 = (wm * 128 + lrow) * 128 + ((khi * 16) ^ xorq);
  const int aK1 = aK0 ^ 64;
  const int bK0 = (wn * 64 + lrow) * 128 + ((khi * 16) ^ xorq);
  const int bK1 = bK0 ^ 64;

  // --- hoisted per-thread staging addresses ---
  // global: row rS = tid>>3 (j=1 adds 64, h adds 128), col-byte cbS (invariant in h,j)
  const int rS = tid >> 3;
  const int cbS = ((tid & 7) * 16) ^ ((rS & 7) << 4);
  const u16* gA = A + (size_t)(m0 + rS) * KDIM + (cbS >> 1);
  const u16* gB = W + (size_t)(n0 + rS) * KDIM + (cbS >> 1);
  const unsigned ldsS = (unsigned)(wid * 1024);  // wave-uniform LDS dest base

  auto stageA = [&](int h, int kt, int p){
    const u16* g0 = gA + h * (128 * KDIM) + kt;
    unsigned l0 = ldsS + (unsigned)(p * 32768 + h * 16384);
    __builtin_amdgcn_global_load_lds((const __attribute__((address_space(1))) void*)g0,
                                     (__attribute__((address_space(3))) void*)(lds + l0), 16, 0, 0);
    __builtin_amdgcn_global_load_lds((const __attribute__((address_space(1))) void*)(g0 + 64 * KDIM),
                                     (__attribute__((address_space(3))) void*)(lds + l0 + 8192), 16, 0, 0);
  };
  auto stageB = [&](int h, int kt, int p){
    const u16* g0 = gB + h * (128 * KDIM) + kt;
    unsigned l0 = ldsS + (unsigned)(65536 + p * 32768 + h * 16384);
    __builtin_amdgcn_global_load_lds((const __attribute__((address_space(1))) void*)g0,
                                     (__attribute__((address_space(3))) void*)(lds + l0), 16, 0, 0);
    __builtin_amdgcn_global_load_lds((const __attribute__((address_space(1))) void*)(g0 + 64 * KDIM),
                                     (__attribute__((address_space(3))) void*)(lds + l0 + 8192), 16, 0, 0);
  };

  const int nIter = KDIM >> 7;   // 2 K-tiles (BK=64) per iteration

  // prologue: B(k0), A(k0) -> buf0 ; B(k1) -> buf1 ; wait all of k0 landed
  stageB(0, 0, 0); stageB(1, 0, 0);
  stageA(0, 0, 0); stageA(1, 0, 0);
  stageB(0, 64, 1); stageB(1, 64, 1);
  asm volatile("s_waitcnt vmcnt(4)" ::: "memory");
  __builtin_amdgcn_s_barrier();

  for (int i = 0; i < nIter; ++i){
    const bool pre = (i < nIter - 1);
    const int ktA1 = (2 * i + 1) << 6;   // K-tile k1 (consumed this iter, phases 4-7)
    const int ktN  = (2 * i + 2) << 6;   // K-tile k2 (next iter, buf0)
    const int ktN1 = (2 * i + 3) << 6;   // K-tile k3 (next iter, buf1)
#pragma unroll
    for (int half = 0; half < 2; ++half){        // K-tile 2i+half from buffer `half`
#pragma unroll
      for (int q = 0; q < 4; ++q){               // phase within K-tile
        // --- ds reads for this phase's MFMAs (addr = hoisted VGPR + literal offset) ---
        if (q == 0){
          const char* pb = lds + (65536 + half * 32768);
#pragma unroll
          for (int nf = 0; nf < 4; nf++){
            bfrag[nf][0] = *(const short8*)(pb + bK0 + nf * 2048);
            bfrag[nf][1] = *(const short8*)(pb + bK1 + nf * 2048);
          }
        }
        short8 a[2][2];
#pragma unroll
        for (int mi = 0; mi < 2; mi++){
          const char* pa = lds + (half * 32768 + (q * 2 + mi) * 2048);
          a[mi][0] = *(const short8*)(pa + aK0);
          a[mi][1] = *(const short8*)(pa + aK1);
        }
        // --- stage one half-tile (region freed >=1 barrier-pair ago) ---
        const int g = half * 4 + q;
        if      (g == 0){ stageA(0, ktA1, 1); }
        else if (g == 1){ stageA(1, ktA1, 1); }
        else if (g == 2){ if (pre) stageB(0, ktN, 0); }
        else if (g == 3){ if (pre) stageB(1, ktN, 0); }
        else if (g == 4){ if (pre) stageA(0, ktN, 0); }
        else if (g == 5){ if (pre) stageA(1, ktN, 0); }
        else if (g == 6){ if (pre) stageB(0, ktN1, 1); }
        else            { if (pre) stageB(1, ktN1, 1); }
        __builtin_amdgcn_s_barrier();
        __builtin_amdgcn_s_setprio(1);
#pragma unroll
        for (int ks = 0; ks < 2; ks++)
#pragma unroll
          for (int mi = 0; mi < 2; mi++)
#pragma unroll
            for (int nf = 0; nf < 4; nf++)
              acc[q * 2 + mi][nf] = __builtin_amdgcn_mfma_f32_16x16x32_bf16(
                  a[mi][ks], bfrag[nf][ks], acc[q * 2 + mi][nf], 0, 0, 0);
        __builtin_amdgcn_s_setprio(0);
        if (q == 3){
          if (pre) asm volatile("s_waitcnt vmcnt(4)" ::: "memory");
          else     asm volatile("s_waitcnt vmcnt(0)" ::: "memory");
        }
        __builtin_amdgcn_s_barrier();
      }
    }
  }

  // epilogue: D row = (lane>>4)*4 + i, col = lane&15 (m89-verified layout)
  float bv[4];
#pragma unroll
  for (int nf = 0; nf < 4; nf++) bv[nf] = bias[n0 + wn * 64 + nf * 16 + lrow];
#pragma unroll
  for (int mf = 0; mf < 8; mf++){
    int r0 = m0 + wm * 128 + mf * 16 + khi * 4;
#pragma unroll
    for (int nf = 0; nf < 4; nf++){
      int c = n0 + wn * 64 + nf * 16 + lrow;
#pragma unroll
      for (int i2 = 0; i2 < 4; i2++){
        float val = acc[mf][nf][i2] + bv[nf];
        size_t o = (size_t)(r0 + i2) * N + c;
        if (EPI == 0) outb[o] = f2bf(val);
        else          outf[o] = val + resid[o];
      }
    }
  }
}

// ---------------- depthwise causal conv1d (K=4), short8-vectorized ----------------
__global__ void conv_kernel(const u16* __restrict__ uv, const float* __restrict__ wc,
                            const float* __restrict__ bc, u16* __restrict__ uc){
  int idx = blockIdx.x * 256 + threadIdx.x;   // over MROWS*1024/8
  int d0 = (idx & 127) * 8;
  int m = idx >> 7;
  int l = m & (SEQ - 1);
  float acc[8];
  float4 wv[8];
#pragma unroll
  for (int j = 0; j < 8; j++){ acc[j] = bc[d0 + j]; wv[j] = *(const float4*)(wc + (d0 + j) * 4); }
#pragma unroll
  for (int k = 0; k < 4; k++){
    int ll = l - 3 + k;
    if (ll >= 0){
      short8 v = *(const short8*)(uv + (size_t)(m - 3 + k) * 2048 + d0);
#pragma unroll
      for (int j = 0; j < 8; j++) acc[j] += bf2f((u16)v[j]) * wv[j][k];
    }
  }
  short8 o;
#pragma unroll
  for (int j = 0; j < 8; j++) o[j] = (short)f2bf(acc[j]);
  *(short8*)(uc + (size_t)m * 1024 + d0) = o;
}

// ---------------- selective scan, pass A ----------------
__global__ void scanA(const u16* __restrict__ dbc, const u16* __restrict__ uc,
                      float* __restrict__ P, float* __restrict__ S){
  int idx = blockIdx.x * 256 + threadIdx.x;   // over BATCH*NCHUNK*1024
  int n = idx & 1023;
  int c = (idx >> 10) & (NCHUNK - 1);
  int b = idx >> 16;
  size_t mbase = (size_t)b * SEQ + c * CHUNK;
  float Pv = 1.f, Sv = 0.f;
  for (int t = 0; t < CHUNK; t++){
    size_t m = mbase + t;
    float dr = bf2f(dbc[m * 3072 + n]);
    float bm = bf2f(dbc[m * 3072 + 1024 + n]);
    float u  = bf2f(uc[m * 1024 + n]);
    float dec = 1.f / (1.f + __expf(dr));   // exp(-softplus(dr)) == sigmoid(-dr)
    Pv *= dec;
    Sv = Sv * dec + u * bm;
  }
  P[idx] = Pv; S[idx] = Sv;
}

// ---------------- pass B: chunk-level scan ----------------
__global__ void scanB(const float* __restrict__ P, const float* __restrict__ S,
                      float* __restrict__ Hin){
  int idx = blockIdx.x * 256 + threadIdx.x;  // over BATCH*1024
  int n = idx & 1023, b = idx >> 10;
  float H = 0.f;
  for (int c = 0; c < NCHUNK; c++){
    int o = (b * NCHUNK + c) * 1024 + n;
    Hin[o] = H;
    H = H * P[o] + S[o];
  }
}

// ---------------- pass C: recompute + reduce y[b,t] ----------------
__global__ __launch_bounds__(1024) void scanC(const u16* __restrict__ dbc, const u16* __restrict__ uc,
                                              const float* __restrict__ Hin, float* __restrict__ y){
  int b = blockIdx.x >> 6, c = blockIdx.x & (NCHUNK - 1);
  int n = threadIdx.x, wid = n >> 6, lane = n & 63;
  __shared__ float part[CHUNK][16];
  float h = Hin[(b * NCHUNK + c) * 1024 + n];
  size_t mbase = (size_t)b * SEQ + c * CHUNK;
  for (int t = 0; t < CHUNK; t++){
    size_t m = mbase + t;
    float dr = bf2f(dbc[m * 3072 + n]);
    float bm = bf2f(dbc[m * 3072 + 1024 + n]);
    float cm = bf2f(dbc[m * 3072 + 2048 + n]);
    float u  = bf2f(uc[m * 1024 + n]);
    float dec = 1.f / (1.f + __expf(dr));
    h = h * dec + u * bm;
    float contrib = h * cm;
#pragma unroll
    for (int off = 32; off > 0; off >>= 1) contrib += __shfl_down(contrib, off);
    if (lane == 0) part[t][wid] = contrib;
  }
  __syncthreads();
  if (n < CHUNK){
    float s = 0.f;
#pragma unroll
    for (int w2 = 0; w2 < 16; w2++) s += part[n][w2];
    y[mbase + n] = s;
  }
}

// ---------------- gate, short8-vectorized ----------------
__global__ void gate_kernel(const u16* __restrict__ uv, const float* __restrict__ y,
                            u16* __restrict__ gg){
  int idx = blockIdx.x * 256 + threadIdx.x;   // over MROWS*1024/8
  int d0 = (idx & 127) * 8;
  int m = idx >> 7;
  short8 v = *(const short8*)(uv + (size_t)m * 2048 + D_MODEL + d0);
  float yv_ = y[m];
  short8 o;
#pragma unroll
  for (int j = 0; j < 8; j++){
    float vf = bf2f((u16)v[j]);
    float s = 1.f / (1.f + __expf(-vf));
    o[j] = (short)f2bf(yv_ * s);
  }
  *(short8*)(gg + (size_t)m * 1024 + d0) = o;
}

extern "C" void kernel_launch(void* const* d_in, const int* in_sizes, int n_in,
                              void* d_out, int out_size, void* d_ws, size_t ws_size,
                              hipStream_t stream) {
  const float* x      = (const float*)d_in[0];
  const float* ln_g   = (const float*)d_in[1];
  const float* ln_b   = (const float*)d_in[2];
  const float* w_in   = (const float*)d_in[3];
  const float* b_in   = (const float*)d_in[4];
  const float* w_conv = (const float*)d_in[5];
  const float* b_conv = (const float*)d_in[6];
  const float* w_delta= (const float*)d_in[7];
  const float* b_delta= (const float*)d_in[8];
  const float* w_B    = (const float*)d_in[9];
  const float* b_B    = (const float*)d_in[10];
  const float* w_C    = (const float*)d_in[11];
  const float* b_C    = (const float*)d_in[12];
  const float* w_out  = (const float*)d_in[13];
  const float* b_out  = (const float*)d_in[14];

  char* w = (char*)d_ws;
  u16* w_in_bf  = (u16*)w; w += (size_t)2 * 1024 * 1024 * 2;   // 4 MB
  u16* wcat_bf  = (u16*)w; w += (size_t)3 * 1024 * 1024 * 2;   // 6 MB (delta|B|C rows)
  u16* w_out_bf = (u16*)w; w += (size_t)1024 * 1024 * 2;       // 2 MB
  float* bcat   = (float*)w; w += 16384;                        // 3072 floats, padded
  u16* h_bf     = (u16*)w; w += (size_t)MROWS * 1024 * 2;      // 32 MB
  u16* uv_bf    = (u16*)w; w += (size_t)MROWS * 2048 * 2;      // 64 MB
  u16* uc_bf    = (u16*)w; w += (size_t)MROWS * 1024 * 2;      // 32 MB
  u16* dbc_bf   = (u16*)w; w += (size_t)MROWS * 3072 * 2;      // 96 MB
  float* P      = (float*)w; w += (size_t)BATCH * NCHUNK * 1024 * 4;
  float* S      = (float*)w; w += (size_t)BATCH * NCHUNK * 1024 * 4;
  float* Hin    = (float*)w; w += (size_t)BATCH * NCHUNK * 1024 * 4;
  float* yv     = (float*)w; w += (size_t)MROWS * 4;
  u16* gg       = h_bf;   // reuse: h dead after GEMM1

  // weights -> bf16
  f2bf_vec<<<2048, 256, 0, stream>>>(w_in,    w_in_bf,              2 * 1024 * 1024);
  f2bf_vec<<<1024, 256, 0, stream>>>(w_delta, wcat_bf,              1024 * 1024);
  f2bf_vec<<<1024, 256, 0, stream>>>(w_B,     wcat_bf + 1024*1024,  1024 * 1024);
  f2bf_vec<<<1024, 256, 0, stream>>>(w_C,     wcat_bf + 2*1024*1024,1024 * 1024);
  f2bf_vec<<<1024, 256, 0, stream>>>(w_out,   w_out_bf,             1024 * 1024);
  hipMemcpyAsync(bcat,        b_delta, 1024 * sizeof(float), hipMemcpyDeviceToDevice, stream);
  hipMemcpyAsync(bcat + 1024, b_B,     1024 * sizeof(float), hipMemcpyDeviceToDevice, stream);
  hipMemcpyAsync(bcat + 2048, b_C,     1024 * sizeof(float), hipMemcpyDeviceToDevice, stream);

  ln_kernel<<<MROWS, 256, 0, stream>>>(x, ln_g, ln_b, h_bf);

  // in_proj: uv[16384,2048]
  gemm256<0><<<dim3((2048/256) * (MROWS/256)), 512, 0, stream>>>(
      h_bf, w_in_bf, b_in, uv_bf, nullptr, nullptr, 2048);

  conv_kernel<<<(MROWS * 1024 / 8) / 256, 256, 0, stream>>>(uv_bf, w_conv, b_conv, uc_bf);

  // delta|B|C fused: dbc[16384,3072]
  gemm256<0><<<dim3((3072/256) * (MROWS/256)), 512, 0, stream>>>(
      uc_bf, wcat_bf, bcat, dbc_bf, nullptr, nullptr, 3072);

  scanA<<<(BATCH * NCHUNK * 1024) / 256, 256, 0, stream>>>(dbc_bf, uc_bf, P, S);
  scanB<<<(BATCH * 1024) / 256, 256, 0, stream>>>(P, S, Hin);
  scanC<<<BATCH * NCHUNK, 1024, 0, stream>>>(dbc_bf, uc_bf, Hin, yv);

  gate_kernel<<<(MROWS * 1024 / 8) / 256, 256, 0, stream>>>(uv_bf, yv, gg);

  // out_proj + bias + residual -> d_out (fp32)
  gemm256<1><<<dim3((1024/256) * (MROWS/256)), 512, 0, stream>>>(
      gg, w_out_bf, b_out, nullptr, (float*)d_out, x, 1024);
}